// Round 9
// baseline (261.793 us; speedup 1.0000x reference)
//
#include <hip/hip_runtime.h>
#include <hip/hip_bf16.h>
#include <stdint.h>

#define N_NODES 100000
#define N_EDGES 600000
#define D 128
#define EPS 1e-5f
#define SCAN_BS 512
#define ROW_MASK 0x1FFFF

#define PREP_BLOCKS 321            // (82048+255)/256
#define HIST_BLOCKS 2344           // (N_EDGES+255)/256, 256-thread histogram blocks (K1)
#define XF_BLOCKS   3125           // N_NODES/32, 64-thread 1-wave xform blocks (K3)
#define SC_BLOCKS   2344           // (N_EDGES/4+63)/64, 64-thread x 4-edge scatter blocks (K3)
#define AU_BLOCKS   3125           // N_NODES/32, 256-thread 4-wave blocks (K4 merged)

typedef __attribute__((ext_vector_type(8))) short short8;
typedef __attribute__((ext_vector_type(16))) float floatx16;

// ---------- helpers ----------

__device__ __forceinline__ uint32_t pack_bf16_rne(float lo, float hi) {
    uint32_t ul = __builtin_bit_cast(uint32_t, lo);
    uint32_t uh = __builtin_bit_cast(uint32_t, hi);
    ul += 0x7fffu + ((ul >> 16) & 1u);
    uh += 0x7fffu + ((uh >> 16) & 1u);
    return (ul >> 16) | (uh & 0xffff0000u);
}

__device__ __forceinline__ unsigned short f32_to_bf16_rne(float f) {
    uint32_t u = __builtin_bit_cast(uint32_t, f);
    u += 0x7fffu + ((u >> 16) & 1u);
    return (unsigned short)(u >> 16);
}

__device__ __forceinline__ float bflo(uint32_t a) { return __builtin_bit_cast(float, a << 16); }
__device__ __forceinline__ float bfhi(uint32_t a) { return __builtin_bit_cast(float, a & 0xffff0000u); }

// ---------- K1: fused weight preprocessing + destination histogram (+rank) ----------
__global__ void prep_hist(const float* __restrict__ w_m1, const float* __restrict__ w_u1,
                          const float* __restrict__ w_u2, const float* __restrict__ w_m2,
                          const float* __restrict__ b_m2,
                          unsigned short* __restrict__ wm1f, unsigned short* __restrict__ wu1tf,
                          unsigned short* __restrict__ wu2f, unsigned short* __restrict__ wcf,
                          float* __restrict__ vb,
                          const int* __restrict__ col, int* __restrict__ count,
                          int* __restrict__ rank) {
    if (blockIdx.x >= PREP_BLOCKS) {
        int e = (blockIdx.x - PREP_BLOCKS) * 256 + threadIdx.x;
        if (e < N_EDGES) rank[e] = atomicAdd(&count[col[e]], 1);
        return;
    }
    int idx = blockIdx.x * 256 + threadIdx.x;
    if (idx < 32768) {
        int j = idx & 7, lane = (idx >> 3) & 63, t = (idx >> 9) & 3, s = idx >> 11;
        int kk = s * 16 + ((lane >> 5) << 3) + j;
        wm1f[idx] = f32_to_bf16_rne(w_m1[kk * 128 + t * 32 + (lane & 31)]);
    } else if (idx < 49152) {
        int ii = idx - 32768;
        int j = ii & 7, lane = (ii >> 3) & 63, t = (ii >> 9) & 3, s = ii >> 11;
        int kk = s * 16 + ((lane >> 5) << 3) + j;
        wu1tf[ii] = f32_to_bf16_rne(w_u1[kk * 128 + t * 32 + (lane & 31)]);
    } else if (idx < 65536) {
        int ii = idx - 49152;
        int j = ii & 7, lane = (ii >> 3) & 63, t = (ii >> 9) & 3, s = ii >> 11;
        int kk = s * 16 + ((lane >> 5) << 3) + j;
        wu2f[ii] = f32_to_bf16_rne(w_u2[kk * 128 + t * 32 + (lane & 31)]);
    } else if (idx < 81920) {
        int ii = idx - 65536;
        int j = ii & 7, lane = (ii >> 3) & 63, t = (ii >> 9) & 3, s = ii >> 11;
        int kk = s * 16 + ((lane >> 5) << 3) + j;
        int nn = t * 32 + (lane & 31);
        float acc = 0.0f;
        for (int q = 0; q < 128; ++q)
            acc += w_m2[kk * 128 + q] * w_u1[(128 + q) * 128 + nn];
        wcf[ii] = f32_to_bf16_rne(acc);
    } else if (idx < 82048) {
        int nn = idx - 81920;
        float acc = 0.0f;
        for (int q = 0; q < 128; ++q)
            acc += b_m2[q] * w_u1[(128 + q) * 128 + nn];
        vb[nn] = acc;
    }
}

// ---------- K2: single-kernel scan ----------
__global__ void scan_one(const int* __restrict__ count, int* __restrict__ base,
                         int* __restrict__ gcur) {
    __shared__ int tmp[SCAN_BS];
    __shared__ int bbase;
    int g = blockIdx.x * SCAN_BS + threadIdx.x;
    int v = (g < N_NODES) ? count[g] : 0;
    tmp[threadIdx.x] = v;
    __syncthreads();
    int acc = v;
#pragma unroll
    for (int off = 1; off < SCAN_BS; off <<= 1) {
        int add = (threadIdx.x >= off) ? tmp[threadIdx.x - off] : 0;
        __syncthreads();
        acc += add;
        tmp[threadIdx.x] = acc;
        __syncthreads();
    }
    if (threadIdx.x == SCAN_BS - 1) bbase = atomicAdd(gcur, acc);
    __syncthreads();
    if (g < N_NODES) base[g] = bbase + acc - v;
}

// ---------- K3: fused xform (XT|XB+b1 bf16 [node][256]) + atomic-free edge scatter ----------
__launch_bounds__(64, 4)
__global__ void xform_scatter(const float* __restrict__ x, const short8* __restrict__ w1f,
                              const float* __restrict__ b1, unsigned short* __restrict__ xtb,
                              const int* __restrict__ row, const int* __restrict__ col,
                              const int* __restrict__ rank, const int* __restrict__ base,
                              int* __restrict__ srow) {
    if (blockIdx.x >= XF_BLOCKS) {
        int e4 = (((blockIdx.x - XF_BLOCKS) * 64 + threadIdx.x) << 2);
        if (e4 < N_EDGES) {
            int4 r4 = *(const int4*)(row + e4);
            int4 c4 = *(const int4*)(col + e4);
            int4 k4 = *(const int4*)(rank + e4);
            srow[base[c4.x] + k4.x] = r4.x | ((c4.x & 31) << 17);
            srow[base[c4.y] + k4.y] = r4.y | ((c4.y & 31) << 17);
            srow[base[c4.z] + k4.z] = r4.z | ((c4.z & 31) << 17);
            srow[base[c4.w] + k4.w] = r4.w | ((c4.w & 31) << 17);
        }
        return;
    }

    __shared__ __align__(16) short h1[32 * 136];
    const int lane = threadIdx.x;
    const int l31  = lane & 31;
    const int half = lane >> 5;
    short* hl = h1;

    const int nbase = blockIdx.x * 32;          // 3125*32 == N_NODES exactly
    const int n = nbase + l31;
    const float* px = x + (size_t)n * D + half * 8;

    union { short8 v; uint32_t u[4]; } fa[8];
#pragma unroll
    for (int s = 0; s < 8; ++s) {
        const int off = s * 16;
        float4 a0 = *(const float4*)(px + off);
        float4 a1 = *(const float4*)(px + off + 4);
        fa[s].u[0] = pack_bf16_rne(a0.x, a0.y); fa[s].u[1] = pack_bf16_rne(a0.z, a0.w);
        fa[s].u[2] = pack_bf16_rne(a1.x, a1.y); fa[s].u[3] = pack_bf16_rne(a1.z, a1.w);
    }

#pragma unroll
    for (int p = 0; p < 2; ++p) {
        floatx16 acc[4];
#pragma unroll
        for (int t = 0; t < 4; ++t) acc[t] = (floatx16)0.0f;
#pragma unroll
        for (int s = 0; s < 8; ++s) {
#pragma unroll
            for (int t = 0; t < 4; ++t) {
                short8 wf = w1f[((p * 8 + s) * 4 + t) * 64 + lane];
                acc[t] = __builtin_amdgcn_mfma_f32_32x32x16_bf16(fa[s].v, wf, acc[t], 0, 0, 0);
            }
        }
#pragma unroll
        for (int t = 0; t < 4; ++t) {
            float bias = p ? b1[t * 32 + l31] : 0.0f;
#pragma unroll
            for (int r = 0; r < 16; ++r) {
                int m = (r & 3) + 8 * (r >> 2) + 4 * half;
                hl[m * 136 + t * 32 + l31] = (short)f32_to_bf16_rne(acc[t][r] + bias);
            }
        }
#pragma unroll
        for (int it = 0; it < 8; ++it) {
            int off = it * 512 + lane * 8;
            int r2 = off >> 7;
            int c2 = off & 127;
            short8 v = *(const short8*)(hl + r2 * 136 + c2);
            *(short8*)(xtb + (size_t)(nbase + r2) * 256 + p * 128 + c2) = v;
        }
    }
}

// ---------- K4 (merged): aggregation + update, 4 waves / 32 nodes ----------
// Phase A: wave w aggregates nodes [8w,8w+8) exactly like the proven agg_kernel
// (quarter-wave CSR streams, 8-deep batched gathers, run-merge), hsum flushed to
// LDS (no global round trip). Phase B: the update GEMMs split across the 4 waves
// by output-quarter tt=waveid; LN row-stats via a small cross-wave LDS reduction.
__launch_bounds__(256, 4)
__global__ void aggupd_kernel(const float* __restrict__ x, const uint32_t* __restrict__ xtb32,
                              const int* __restrict__ srowpk,
                              const int* __restrict__ base, const int* __restrict__ count,
                              const short8* __restrict__ wu1tf, const short8* __restrict__ wcf,
                              const short8* __restrict__ wu2f,
                              const float* __restrict__ b_u1, const float* __restrict__ vb,
                              const float* __restrict__ b_u2,
                              const float* __restrict__ gamma, const float* __restrict__ beta,
                              float* __restrict__ out) {
    __shared__ __align__(16) uint32_t accu[32 * 64];   // 8 KB: [32 nodes][64 dwords] bf16 hsum
    __shared__ __align__(16) uint32_t XBl[32 * 64];    // 8 KB: XB prestage
    __shared__ __align__(16) short h1[32 * 136];       // 8.7 KB: h bf16 (reused as hf fp32 16x132)
    __shared__ float partS1[4][32], partS2[4][32];
    __shared__ float meanA[32], rsA[32];

    const int tid  = threadIdx.x;
    const int wv   = tid >> 6;            // wave id == output-quarter tt
    const int lane = tid & 63;
    const int l31  = lane & 31;
    const int half = lane >> 5;
    const int t    = lane & 15;           // lane within quarter
    const int q16  = lane & 48;           // quarter * 16

    const int nbase = blockIdx.x * 32;

    // cooperative: zero accu + prestage 32 XB rows
    {
        uint4 z; z.x = 0; z.y = 0; z.z = 0; z.w = 0;
        *((uint4*)accu + tid) = z;
        *((uint4*)accu + 256 + tid) = z;
#pragma unroll
        for (int it = 0; it < 2; ++it) {
            int fi4 = it * 256 + tid;                    // uint4 index 0..511
            int i = fi4 >> 4, k4 = fi4 & 15;
            *((uint4*)XBl + fi4) = *(const uint4*)(xtb32 + (size_t)(nbase + i) * 128 + 64 + (k4 << 2));
        }
    }
    __syncthreads();

    // ---- Phase A (per wave, nodes [nbase+8wv, +8)) ----
    {
        const int nodew = nbase + 8 * wv;
        const int b_l = base[nodew + (lane & 7)];
        const int c_l = count[nodew + (lane & 7)];
        const int qsrc = q16 >> 3;                       // 2*quarter
        const int qbeg = __shfl(b_l, qsrc);
        const int qend = __shfl(b_l, qsrc + 1) + __shfl(c_l, qsrc + 1);
        const int rembase = qend - qbeg;

        int ncm = (rembase + 7) >> 3;                    // chunks of 8 edges per quarter
        ncm = max(ncm, __shfl_xor(ncm, 16));
        ncm = max(ncm, __shfl_xor(ncm, 32));             // wave-uniform max

        float sl0 = 0.f, sl1 = 0.f, sl2 = 0.f, sl3 = 0.f;
        float sh0 = 0.f, sh1 = 0.f, sh2 = 0.f, sh3 = 0.f;
        int curnib = -1;

        auto flush = [&]() {
            uint4 o;
            o.x = pack_bf16_rne(sl0, sh0);
            o.y = pack_bf16_rne(sl1, sh1);
            o.z = pack_bf16_rne(sl2, sh2);
            o.w = pack_bf16_rne(sl3, sh3);
            *(uint4*)(accu + (curnib << 6) + (t << 2)) = o;
        };

        for (int c = 0; c < ncm; ++c) {
            int idx = qbeg + (c << 3) + (t & 7);
            int pk = srowpk[min(idx, N_EDGES - 1)];
            const int rem = rembase - (c << 3);          // quarter-uniform remaining

            uint4 xt[8]; int pv[8];
#pragma unroll
            for (int e = 0; e < 8; ++e) {
                int p = __shfl(pk, q16 + e);
                if (e >= rem) p = 0;                     // invalid -> row 0 (L1-hot)
                pv[e] = p;
                xt[e] = *(const uint4*)(xtb32 + (size_t)(p & ROW_MASK) * 128 + (t << 2));
            }
            __builtin_amdgcn_sched_barrier(0);
#pragma unroll
            for (int e = 0; e < 8; ++e) {
                if (e < rem) {
                    int nib = pv[e] >> 17;               // node within 32-group
                    uint4 xb = *(const uint4*)(XBl + (nib << 6) + (t << 2));
                    float a0 = fmaxf(bflo(xt[e].x) + bflo(xb.x), 0.f);
                    float b0 = fmaxf(bfhi(xt[e].x) + bfhi(xb.x), 0.f);
                    float a1 = fmaxf(bflo(xt[e].y) + bflo(xb.y), 0.f);
                    float b1 = fmaxf(bfhi(xt[e].y) + bfhi(xb.y), 0.f);
                    float a2 = fmaxf(bflo(xt[e].z) + bflo(xb.z), 0.f);
                    float b2 = fmaxf(bfhi(xt[e].z) + bfhi(xb.z), 0.f);
                    float a3 = fmaxf(bflo(xt[e].w) + bflo(xb.w), 0.f);
                    float b3 = fmaxf(bfhi(xt[e].w) + bfhi(xb.w), 0.f);
                    if (nib != curnib) {
                        if (curnib >= 0) flush();
                        curnib = nib;
                        sl0 = a0; sh0 = b0; sl1 = a1; sh1 = b1;
                        sl2 = a2; sh2 = b2; sl3 = a3; sh3 = b3;
                    } else {
                        sl0 += a0; sh0 += b0; sl1 += a1; sh1 += b1;
                        sl2 += a2; sh2 += b2; sl3 += a3; sh3 += b3;
                    }
                }
            }
        }
        if (curnib >= 0) flush();
    }
    __syncthreads();

    // ---- Phase B: wave wv computes output cols [32wv, 32wv+32) for all 32 nodes ----
    const int nc = nbase + l31;
    const float dgv = (float)count[nc];
    const float* px = x + (size_t)nc * D + half * 8;

    const float bu1  = b_u1[wv * 32 + l31];
    const float vbt  = vb[wv * 32 + l31];
    const float bias2 = b_u2[wv * 32 + l31];
    const float gA   = gamma[wv * 32 + l31];
    const float beA  = beta[wv * 32 + l31];

    // GEMM1: x@Wu1top (K=128) + hsum@Wc (K=128), tt = wv
    floatx16 acc = (floatx16)0.0f;
#pragma unroll
    for (int s = 0; s < 8; ++s) {
        union { short8 v; uint32_t u[4]; } fa;
        const int off = s * 16;
        float4 a0 = *(const float4*)(px + off);
        float4 a1 = *(const float4*)(px + off + 4);
        fa.u[0] = pack_bf16_rne(a0.x, a0.y); fa.u[1] = pack_bf16_rne(a0.z, a0.w);
        fa.u[2] = pack_bf16_rne(a1.x, a1.y); fa.u[3] = pack_bf16_rne(a1.z, a1.w);
        short8 wf = wu1tf[(s * 4 + wv) * 64 + lane];
        acc = __builtin_amdgcn_mfma_f32_32x32x16_bf16(fa.v, wf, acc, 0, 0, 0);
    }
#pragma unroll
    for (int s = 0; s < 8; ++s) {
        short8 fh = *(const short8*)((const short*)accu + l31 * 128 + s * 16 + half * 8);
        short8 wf = wcf[(s * 4 + wv) * 64 + lane];
        acc = __builtin_amdgcn_mfma_f32_32x32x16_bf16(fh, wf, acc, 0, 0, 0);
    }

    // ReLU(acc + b_u1 + deg*vb) -> h (bf16, LDS)
#pragma unroll
    for (int r = 0; r < 16; ++r) {
        int m = (r & 3) + 8 * (r >> 2) + 4 * half;
        float dg = __shfl(dgv, m, 32);
        float v = fmaxf(acc[r] + bu1 + dg * vbt, 0.0f);
        h1[m * 136 + wv * 32 + l31] = (short)f32_to_bf16_rne(v);
    }
    __syncthreads();

    // GEMM2: h@Wu2, tt = wv
    short8 af[8];
#pragma unroll
    for (int s = 0; s < 8; ++s)
        af[s] = *(const short8*)(h1 + l31 * 136 + s * 16 + half * 8);
    floatx16 acc2 = (floatx16)0.0f;
#pragma unroll
    for (int s = 0; s < 8; ++s) {
        short8 wf = wu2f[(s * 4 + wv) * 64 + lane];
        acc2 = __builtin_amdgcn_mfma_f32_32x32x16_bf16(af[s], wf, acc2, 0, 0, 0);
    }

    // LN partials: per-wave 32-col sums per row, then cross-wave totals
#pragma unroll
    for (int r = 0; r < 16; ++r) {
        float hv = acc2[r] + bias2;
        float s1 = hv, s2 = hv * hv;
#pragma unroll
        for (int mask = 1; mask < 32; mask <<= 1) {
            s1 += __shfl_xor(s1, mask);
            s2 += __shfl_xor(s2, mask);
        }
        int m = (r & 3) + 8 * (r >> 2) + 4 * half;
        if (l31 == 0) { partS1[wv][m] = s1; partS2[wv][m] = s2; }
    }
    __syncthreads();
    if (tid < 32) {
        int m = tid;
        float s1 = partS1[0][m] + partS1[1][m] + partS1[2][m] + partS1[3][m];
        float s2 = partS2[0][m] + partS2[1][m] + partS2[2][m] + partS2[3][m];
        float mean = s1 * (1.0f / 128.0f);
        float var  = s2 * (1.0f / 128.0f) - mean * mean;
        meanA[m] = mean;
        rsA[m]   = rsqrtf(var + EPS);
    }
    __syncthreads();

    // Epilogue: two 16-row passes through hf (reuses h1 region), coalesced stores
    float* hf = (float*)h1;
#pragma unroll
    for (int p = 0; p < 2; ++p) {
#pragma unroll
        for (int r = 0; r < 16; ++r) {
            int m = (r & 3) + 8 * (r >> 2) + 4 * half;
            int mrow = m - 16 * p;
            if (mrow >= 0 && mrow < 16) {
                float hv = acc2[r] + bias2;
                hf[mrow * 132 + wv * 32 + l31] = (hv - meanA[m]) * rsA[m] * gA + beA;
            }
        }
        __syncthreads();
#pragma unroll
        for (int it = 0; it < 2; ++it) {
            int q = it * 256 + tid;
            int r2 = q >> 5;
            int c4 = q & 31;
            int node = nbase + 16 * p + r2;
            float4 v = *(const float4*)(hf + r2 * 132 + c4 * 4);
            float4 xr = *(const float4*)(x + (size_t)node * D + c4 * 4);
            v.x += xr.x; v.y += xr.y; v.z += xr.z; v.w += xr.w;
            *(float4*)(out + (size_t)node * D + c4 * 4) = v;
        }
        __syncthreads();
    }
}

// ---------- launch ----------
extern "C" void kernel_launch(void* const* d_in, const int* in_sizes, int n_in,
                              void* d_out, int out_size, void* d_ws, size_t ws_size,
                              hipStream_t stream) {
    const float* x     = (const float*)d_in[0];
    const int*   edge  = (const int*)d_in[1];
    const float* w_m1  = (const float*)d_in[2];
    const float* b_m1  = (const float*)d_in[3];
    const float* w_m2  = (const float*)d_in[4];
    const float* b_m2  = (const float*)d_in[5];
    const float* w_u1  = (const float*)d_in[6];
    const float* b_u1  = (const float*)d_in[7];
    const float* w_u2  = (const float*)d_in[8];
    const float* b_u2  = (const float*)d_in[9];
    const float* gamma = (const float*)d_in[10];
    const float* beta  = (const float*)d_in[11];
    float* out = (float*)d_out;

    char* ws = (char*)d_ws;
    size_t off = 0;
    auto alloc = [&](size_t bytes) { void* p = ws + off; off = (off + bytes + 15) & ~(size_t)15; return p; };

    unsigned short* xtb   = (unsigned short*)alloc((size_t)N_NODES * 256 * 2);  // XT | XB+b1
    unsigned short* wm1f  = (unsigned short*)alloc(256 * 128 * 2);
    unsigned short* wu1tf = (unsigned short*)alloc(128 * 128 * 2);
    unsigned short* wcf   = (unsigned short*)alloc(128 * 128 * 2);
    unsigned short* wu2f  = (unsigned short*)alloc(128 * 128 * 2);
    float* vb    = (float*)alloc(128 * 4);
    int* count   = (int*)alloc((size_t)N_NODES * 4 + 16);   // + gcur tail
    int* gcur    = count + N_NODES;
    int* base    = (int*)alloc((size_t)N_NODES * 4);
    int* rank    = (int*)alloc((size_t)N_EDGES * 4);
    int* srow    = (int*)alloc((size_t)N_EDGES * 4);

    const int* rowi = edge;            // edge_index[0]
    const int* coli = edge + N_EDGES;  // edge_index[1]
    const int NB = (N_NODES + SCAN_BS - 1) / SCAN_BS;  // 196 blocks

    (void)hipMemsetAsync(count, 0, (size_t)N_NODES * 4 + 16, stream);  // count + gcur

    // K1: all weight prep + destination histogram (+rank harvest)
    prep_hist<<<PREP_BLOCKS + HIST_BLOCKS, 256, 0, stream>>>(
        w_m1, w_u1, w_u2, w_m2, b_m2, wm1f, wu1tf, wu2f, wcf, vb, coli, count, rank);

    // K2: single-kernel scan
    scan_one<<<NB, SCAN_BS, 0, stream>>>(count, base, gcur);

    // K3: xform + atomic-free packed edge scatter fused
    xform_scatter<<<XF_BLOCKS + SC_BLOCKS, 64, 0, stream>>>(
        x, (const short8*)wm1f, b_m1, xtb, rowi, coli, rank, base, srow);

    // K4 merged: aggregation (4x8 nodes/wave, LDS hsum) + update (tt-split GEMMs)
    aggupd_kernel<<<AU_BLOCKS, 256, 0, stream>>>(
        x, (const uint32_t*)xtb, srow, base, count,
        (const short8*)wu1tf, (const short8*)wcf, (const short8*)wu2f,
        b_u1, vb, b_u2, gamma, beta, out);
}